// Round 1
// baseline (240.253 us; speedup 1.0000x reference)
//
#include <hip/hip_runtime.h>
#include <hip/hip_bf16.h>

typedef __attribute__((ext_vector_type(8))) short bf16x8;
typedef __attribute__((ext_vector_type(4))) float f32x4;

static constexpr int BB = 2, T = 2048, C = 1024, NH = 16, DH = 64;

__device__ __forceinline__ void gload16(const void* g, void* l) {
  __builtin_amdgcn_global_load_lds(
      (const __attribute__((address_space(1))) unsigned int*)g,
      (__attribute__((address_space(3))) unsigned int*)l, 16, 0, 0);
}

// ---------------- convert fp32 -> bf16 (vectorized) ----------------
__global__ __launch_bounds__(256) void k_cvt_bf16(const float* __restrict__ in,
                                                  __hip_bfloat16* __restrict__ out, int n4) {
  int i = blockIdx.x * blockDim.x + threadIdx.x;
  if (i >= n4) return;
  float4 v = reinterpret_cast<const float4*>(in)[i];
  __hip_bfloat16 h[4];
  h[0] = __float2bfloat16(v.x); h[1] = __float2bfloat16(v.y);
  h[2] = __float2bfloat16(v.z); h[3] = __float2bfloat16(v.w);
  reinterpret_cast<uint2*>(out)[i] = *reinterpret_cast<uint2*>(h);
}

// ------------- transpose + convert: in[K][N] fp32 -> out[N][K] bf16 -------------
__global__ __launch_bounds__(256) void k_transpose_cvt(const float* __restrict__ in,
                                                       __hip_bfloat16* __restrict__ out,
                                                       int K, int N) {
  __shared__ float tile[32][33];
  int n0 = blockIdx.x * 32, k0 = blockIdx.y * 32;
  int tx = threadIdx.x, ty = threadIdx.y;  // 32 x 8
#pragma unroll
  for (int i = 0; i < 32; i += 8)
    tile[ty + i][tx] = in[(size_t)(k0 + ty + i) * N + n0 + tx];
  __syncthreads();
#pragma unroll
  for (int i = 0; i < 32; i += 8)
    out[(size_t)(n0 + ty + i) * K + k0 + tx] = __float2bfloat16(tile[tx][ty + i]);
}

// ---------------- 128x128 bf16 MFMA GEMM, A[M][K] * Bt[N][K]^T ----------------
// EPI 0: qkv scatter into Q[b,h,t,d] (x0.125), K[b,h,t,d], Vt[b,h,d,t] (bf16)
// EPI 1: fp32 out[M][N] + bias
template <int EPI>
__global__ __launch_bounds__(256) void k_gemm128(
    const __hip_bfloat16* __restrict__ A, const __hip_bfloat16* __restrict__ Bt,
    const float* __restrict__ bias, int K, int N,
    __hip_bfloat16* __restrict__ oq, __hip_bfloat16* __restrict__ okk,
    __hip_bfloat16* __restrict__ ovt, float* __restrict__ of) {
  __shared__ __align__(16) __hip_bfloat16 As[128 * 32];
  __shared__ __align__(16) __hip_bfloat16 Bs[128 * 32];
  const int tid = threadIdx.x;
  const int lane = tid & 63;
  const int w = tid >> 6;
  const int wr = w >> 1, wc = w & 1;
  const int lr = lane & 15, lg = lane >> 4;
  const int m0 = blockIdx.x * 128, n0 = blockIdx.y * 128;

  const __hip_bfloat16* Ab = A + (size_t)m0 * K;
  const __hip_bfloat16* Bb = Bt + (size_t)n0 * K;

  // staging geometry: 512 chunks of 16B per tile; chunk = c*256 + tid
  const int row0 = tid >> 2, kg0 = tid & 3;
  const int row1 = 64 + row0;
  __hip_bfloat16* lA0 = As + (size_t)(tid & ~63) * 8;
  __hip_bfloat16* lA1 = As + (size_t)(256 + (tid & ~63)) * 8;
  __hip_bfloat16* lB0 = Bs + (size_t)(tid & ~63) * 8;
  __hip_bfloat16* lB1 = Bs + (size_t)(256 + (tid & ~63)) * 8;

  f32x4 acc[4][4] = {};

  for (int k0 = 0; k0 < K; k0 += 32) {
    gload16(Ab + (size_t)row0 * K + k0 + kg0 * 8, lA0);
    gload16(Ab + (size_t)row1 * K + k0 + kg0 * 8, lA1);
    gload16(Bb + (size_t)row0 * K + k0 + kg0 * 8, lB0);
    gload16(Bb + (size_t)row1 * K + k0 + kg0 * 8, lB1);
    __syncthreads();
    bf16x8 af[4], bfr[4];
#pragma unroll
    for (int mi = 0; mi < 4; ++mi)
      af[mi] = *reinterpret_cast<const bf16x8*>(&As[(wr * 64 + mi * 16 + lr) * 32 + lg * 8]);
#pragma unroll
    for (int ni = 0; ni < 4; ++ni)
      bfr[ni] = *reinterpret_cast<const bf16x8*>(&Bs[(wc * 64 + ni * 16 + lr) * 32 + lg * 8]);
#pragma unroll
    for (int mi = 0; mi < 4; ++mi)
#pragma unroll
      for (int ni = 0; ni < 4; ++ni)
        acc[mi][ni] = __builtin_amdgcn_mfma_f32_16x16x32_bf16(af[mi], bfr[ni], acc[mi][ni], 0, 0, 0);
    __syncthreads();
  }

  float bias_r[4];
#pragma unroll
  for (int ni = 0; ni < 4; ++ni) bias_r[ni] = bias[n0 + wc * 64 + ni * 16 + lr];

  if (EPI == 0) {
    const int region = n0 >> 10;  // 0=Q 1=K 2=V (128 | 1024)
#pragma unroll
    for (int mi = 0; mi < 4; ++mi) {
#pragma unroll
      for (int ni = 0; ni < 4; ++ni) {
        const int n = n0 + wc * 64 + ni * 16 + lr;
        const int cc = n & 1023, h = cc >> 6, d = cc & 63;
#pragma unroll
        for (int r = 0; r < 4; ++r) {
          const int m = m0 + wr * 64 + mi * 16 + lg * 4 + r;
          const int bb = m >> 11, t = m & 2047;
          float v = acc[mi][ni][r] + bias_r[ni];
          if (region == 0) {
            oq[((size_t)(bb * NH + h) * T + t) * DH + d] = __float2bfloat16(v * 0.125f);
          } else if (region == 1) {
            okk[((size_t)(bb * NH + h) * T + t) * DH + d] = __float2bfloat16(v);
          } else {
            ovt[((size_t)(bb * NH + h) * DH + d) * T + t] = __float2bfloat16(v);
          }
        }
      }
    }
  } else {
#pragma unroll
    for (int mi = 0; mi < 4; ++mi)
#pragma unroll
      for (int ni = 0; ni < 4; ++ni) {
        const int n = n0 + wc * 64 + ni * 16 + lr;
#pragma unroll
        for (int r = 0; r < 4; ++r) {
          const int m = m0 + wr * 64 + mi * 16 + lg * 4 + r;
          of[(size_t)m * N + n] = acc[mi][ni][r] + bias_r[ni];
        }
      }
  }
}

// ---------------- flash attention: Q,K [bh][t][d] (Q pre-scaled), Vt [bh][d][t] ----------------
__global__ __launch_bounds__(256, 2) void k_attn(const __hip_bfloat16* __restrict__ Q,
                                                 const __hip_bfloat16* __restrict__ Kc,
                                                 const __hip_bfloat16* __restrict__ Vt,
                                                 __hip_bfloat16* __restrict__ O) {
  __shared__ __align__(16) __hip_bfloat16 Plds[4][32][72];  // per-wave, +8 pad kills b128 conflicts
  const int tid = threadIdx.x;
  const int w = tid >> 6, lane = tid & 63;
  const int lr = lane & 15, lg = lane >> 4;
  const int bh = blockIdx.y;
  const int b = bh >> 4, h = bh & 15;
  const int t0 = blockIdx.x * 128 + w * 32;
  const __hip_bfloat16* Qh = Q + (size_t)bh * T * DH;
  const __hip_bfloat16* Kh = Kc + (size_t)bh * T * DH;
  const __hip_bfloat16* Vh = Vt + (size_t)bh * DH * T;

  bf16x8 q[2][2];
#pragma unroll
  for (int mi = 0; mi < 2; ++mi)
#pragma unroll
    for (int kf = 0; kf < 2; ++kf)
      q[mi][kf] = *reinterpret_cast<const bf16x8*>(
          &Qh[(size_t)(t0 + mi * 16 + lr) * DH + kf * 32 + lg * 8]);

  f32x4 o[2][4] = {};
  float mrun[2][4], lrun[2][4];
#pragma unroll
  for (int mi = 0; mi < 2; ++mi)
#pragma unroll
    for (int r = 0; r < 4; ++r) { mrun[mi][r] = -1e30f; lrun[mi][r] = 0.f; }

  for (int kv = 0; kv < T; kv += 64) {
    bf16x8 bk[4][2];
#pragma unroll
    for (int nj = 0; nj < 4; ++nj)
#pragma unroll
      for (int kf = 0; kf < 2; ++kf)
        bk[nj][kf] = *reinterpret_cast<const bf16x8*>(
            &Kh[(size_t)(kv + nj * 16 + lr) * DH + kf * 32 + lg * 8]);

    f32x4 s[2][4] = {};
#pragma unroll
    for (int mi = 0; mi < 2; ++mi)
#pragma unroll
      for (int nj = 0; nj < 4; ++nj) {
        s[mi][nj] = __builtin_amdgcn_mfma_f32_16x16x32_bf16(q[mi][0], bk[nj][0], s[mi][nj], 0, 0, 0);
        s[mi][nj] = __builtin_amdgcn_mfma_f32_16x16x32_bf16(q[mi][1], bk[nj][1], s[mi][nj], 0, 0, 0);
      }

    float al[2][4];
#pragma unroll
    for (int mi = 0; mi < 2; ++mi) {
#pragma unroll
      for (int r = 0; r < 4; ++r) {
        float pm = fmaxf(fmaxf(s[mi][0][r], s[mi][1][r]), fmaxf(s[mi][2][r], s[mi][3][r]));
#pragma unroll
        for (int off = 1; off < 16; off <<= 1) pm = fmaxf(pm, __shfl_xor(pm, off));
        float mn = fmaxf(mrun[mi][r], pm);
        al[mi][r] = __expf(mrun[mi][r] - mn);
        mrun[mi][r] = mn;
        float rs = 0.f;
#pragma unroll
        for (int nj = 0; nj < 4; ++nj) {
          float p = __expf(s[mi][nj][r] - mn);
          s[mi][nj][r] = p;
          rs += p;
        }
#pragma unroll
        for (int off = 1; off < 16; off <<= 1) rs += __shfl_xor(rs, off);
        lrun[mi][r] = lrun[mi][r] * al[mi][r] + rs;
      }
    }

    __syncthreads();  // fence: prior-iter P reads complete before overwrite
#pragma unroll
    for (int mi = 0; mi < 2; ++mi)
#pragma unroll
      for (int nj = 0; nj < 4; ++nj)
#pragma unroll
        for (int r = 0; r < 4; ++r)
          Plds[w][mi * 16 + lg * 4 + r][nj * 16 + lr] = __float2bfloat16(s[mi][nj][r]);
    __syncthreads();  // fence: P writes ordered before A-layout reads

    bf16x8 pa[2][2];
#pragma unroll
    for (int mi = 0; mi < 2; ++mi)
#pragma unroll
      for (int kf = 0; kf < 2; ++kf)
        pa[mi][kf] = *reinterpret_cast<const bf16x8*>(&Plds[w][mi * 16 + lr][kf * 32 + lg * 8]);

    bf16x8 bv[2][4];
#pragma unroll
    for (int kf = 0; kf < 2; ++kf)
#pragma unroll
      for (int nd = 0; nd < 4; ++nd)
        bv[kf][nd] = *reinterpret_cast<const bf16x8*>(
            &Vh[(size_t)(nd * 16 + lr) * T + kv + kf * 32 + lg * 8]);

#pragma unroll
    for (int mi = 0; mi < 2; ++mi)
#pragma unroll
      for (int nd = 0; nd < 4; ++nd) {
#pragma unroll
        for (int r = 0; r < 4; ++r) o[mi][nd][r] *= al[mi][r];
        o[mi][nd] = __builtin_amdgcn_mfma_f32_16x16x32_bf16(pa[mi][0], bv[0][nd], o[mi][nd], 0, 0, 0);
        o[mi][nd] = __builtin_amdgcn_mfma_f32_16x16x32_bf16(pa[mi][1], bv[1][nd], o[mi][nd], 0, 0, 0);
      }
  }

#pragma unroll
  for (int mi = 0; mi < 2; ++mi) {
    float inv[4];
#pragma unroll
    for (int r = 0; r < 4; ++r) inv[r] = 1.0f / lrun[mi][r];
#pragma unroll
    for (int nd = 0; nd < 4; ++nd)
#pragma unroll
      for (int r = 0; r < 4; ++r) {
        const int t = t0 + mi * 16 + lg * 4 + r;
        O[((size_t)(b * T + t)) * C + h * DH + nd * 16 + lr] =
            __float2bfloat16(o[mi][nd][r] * inv[r]);
      }
  }
}

extern "C" void kernel_launch(void* const* d_in, const int* in_sizes, int n_in,
                              void* d_out, int out_size, void* d_ws, size_t ws_size,
                              hipStream_t stream) {
  const float* x      = (const float*)d_in[0];
  const float* w_qkv  = (const float*)d_in[1];
  const float* b_qkv  = (const float*)d_in[2];
  const float* w_proj = (const float*)d_in[3];
  const float* b_proj = (const float*)d_in[4];
  float* out = (float*)d_out;

  // workspace layout (bf16 elems), total 50.3 MB
  __hip_bfloat16* ws  = (__hip_bfloat16*)d_ws;
  __hip_bfloat16* xb  = ws;                    // 4194304  x as bf16 [4096][1024]
  __hip_bfloat16* wqt = xb + 4194304;          // 3145728  w_qkv^T [3072][1024]
  __hip_bfloat16* wpt = wqt + 3145728;         // 1048576  w_proj^T [1024][1024]
  __hip_bfloat16* Qb  = wpt + 1048576;         // 4194304  Q [b,h,t,d] (x0.125)
  __hip_bfloat16* Kb  = Qb + 4194304;          // 4194304  K [b,h,t,d]
  __hip_bfloat16* Vtb = Kb + 4194304;          // 4194304  V^T [b,h,d,t]
  __hip_bfloat16* Ob  = Vtb + 4194304;         // 4194304  attn out [4096][1024]

  k_cvt_bf16<<<4096, 256, 0, stream>>>(x, xb, 1048576);
  k_transpose_cvt<<<dim3(96, 32), dim3(32, 8), 0, stream>>>(w_qkv, wqt, 1024, 3072);
  k_transpose_cvt<<<dim3(32, 32), dim3(32, 8), 0, stream>>>(w_proj, wpt, 1024, 1024);
  k_gemm128<0><<<dim3(32, 24), 256, 0, stream>>>(xb, wqt, b_qkv, 1024, 3072,
                                                 Qb, Kb, Vtb, nullptr);
  k_attn<<<dim3(16, 32), 256, 0, stream>>>(Qb, Kb, Vtb, Ob);
  k_gemm128<1><<<dim3(32, 8), 256, 0, stream>>>(Ob, wpt, b_proj, 1024, 1024,
                                                nullptr, nullptr, nullptr, out);
}